// Round 6
// baseline (64637.305 us; speedup 1.0000x reference)
//
#include <hip/hip_runtime.h>
#include <hip/hip_bf16.h>
#include <math.h>

typedef unsigned short ushort_t;

#define C_DIM 512
#define P_DIM 576
#define SLABF (512 * 576)   /* floats per scratch slab */

__device__ __forceinline__ float bf2f(ushort_t u) {
    union { unsigned int i; float f; } v;
    v.i = ((unsigned int)u) << 16;
    return v.f;
}
__device__ __forceinline__ ushort_t f2bf(float f) {
    union { float f; unsigned int i; } v;
    v.f = f;
    unsigned int r = v.i + 0x7FFFu + ((v.i >> 16) & 1u);
    return (ushort_t)(r >> 16);
}

// Read input element i from a buffer whose true dtype is selected by flag.
__device__ __forceinline__ float in_read(const void* p, size_t i, int is_f32) {
    if (is_f32) return ((const float*)p)[i];
    return bf2f(((const ushort_t*)p)[i]);
}

// ---------------------------------------------------------------------------
// Dtype probe: read first 4096 halves of wq as bf16. True-bf16 weights are
// |v| <= ~0.15; fp32-data-read-as-bf16 yields ~40% wild exponents among even
// halves. Deterministic, device-only, graph-safe.
// ---------------------------------------------------------------------------
__global__ void detect_dtype(const ushort_t* wq_h, int* flag) {
    __shared__ int cnt;
    if (threadIdx.x == 0) cnt = 0;
    __syncthreads();
    int local = 0;
    for (int i = threadIdx.x; i < 4096; i += 256) {
        float v = bf2f(wq_h[i]);
        if (!(fabsf(v) < 1e6f)) local++;   // also true for NaN
    }
    atomicAdd(&cnt, local);
    __syncthreads();
    if (threadIdx.x == 0) flag[0] = (cnt > 10) ? 1 : 0;
}

// ---------------------------------------------------------------------------
// Naive QKV projection for one (b,t): Out[o][p] = sum_c W[o][c]*(x[b][c][t][p]
// + pos[c][t]) + bias[o], fp32 accumulate, fp32 scratch out.
// grid (1152, 3): y = mode (q/k/v). One thread per (o,p).
// ---------------------------------------------------------------------------
__global__ __launch_bounds__(256)
void proj_qkv_naive(const void* x, const void* pos,
                    const void* w0, const void* b0,
                    const void* w1, const void* b1,
                    const void* w2, const void* b2,
                    float* __restrict__ q, float* __restrict__ k, float* __restrict__ v,
                    const int* __restrict__ flag, int b_idx, int t_idx)
{
    const int is_f32 = flag[0];
    const int mode = blockIdx.y;
    const void* W; const void* bias; float* out;
    if (mode == 0)      { W = w0; bias = b0; out = q; }
    else if (mode == 1) { W = w1; bias = b1; out = k; }
    else                { W = w2; bias = b2; out = v; }

    const int idx = blockIdx.x * 256 + threadIdx.x;   // 0 .. 512*576-1
    const int o = idx / 576;
    const int p = idx - o * 576;

    float acc = in_read(bias, o, is_f32);
    for (int c = 0; c < 512; ++c) {
        float xv = in_read(x, ((size_t)(b_idx * 512 + c) * 16 + t_idx) * 576 + p, is_f32)
                 + in_read(pos, c * 16 + t_idx, is_f32);
        acc += in_read(W, (size_t)o * 512 + c, is_f32) * xv;
    }
    out[(size_t)o * 576 + p] = acc;
}

// ---------------------------------------------------------------------------
// Naive attention for one (b,t): one thread per (h,q). fp32 in/out scratch.
// AO overwrites Q in place (per-thread reads own column before writing it;
// thread address sets disjoint).
// ---------------------------------------------------------------------------
__global__ __launch_bounds__(192)
void attn_naive(float* qs, const float* __restrict__ ks, const float* __restrict__ vs)
{
    const int h = blockIdx.y;
    const int q = blockIdx.x * 192 + threadIdx.x;   // 0..575
    const size_t base = (size_t)(h * 64) * 576;

    float Qr[64];
    #pragma unroll
    for (int d = 0; d < 64; ++d)
        Qr[d] = qs[base + (size_t)d * 576 + q] * 0.125f;

    float O[64];
    #pragma unroll
    for (int d = 0; d < 64; ++d) O[d] = 0.f;
    float l = 0.f;

    for (int kv = 0; kv < 576; ++kv) {
        float s = 0.f;
        #pragma unroll
        for (int d = 0; d < 64; ++d)
            s += Qr[d] * ks[base + (size_t)d * 576 + kv];
        float e = __expf(s);
        l += e;
        #pragma unroll
        for (int d = 0; d < 64; ++d)
            O[d] += e * vs[base + (size_t)d * 576 + kv];
    }

    float inv = 1.f / l;
    #pragma unroll
    for (int d = 0; d < 64; ++d)
        qs[base + (size_t)d * 576 + q] = O[d] * inv;
}

// ---------------------------------------------------------------------------
// Naive output projection for one (b,t): d_out[b][o][t][p] =
//   sum_c wo[o][c]*AO[c][p] + bo[o]. Output dtype selected by flag.
// ---------------------------------------------------------------------------
__global__ __launch_bounds__(256)
void proj_out_naive(const float* __restrict__ ao,
                    const void* wo, const void* bo,
                    void* out, const int* __restrict__ flag, int b_idx, int t_idx)
{
    const int is_f32 = flag[0];
    const int idx = blockIdx.x * 256 + threadIdx.x;
    const int o = idx / 576;
    const int p = idx - o * 576;

    float acc = in_read(bo, o, is_f32);
    for (int c = 0; c < 512; ++c)
        acc += in_read(wo, (size_t)o * 512 + c, is_f32) * ao[(size_t)c * 576 + p];

    const size_t addr = ((size_t)(b_idx * 512 + o) * 16 + t_idx) * 576 + p;
    if (is_f32) ((float*)out)[addr] = acc;
    else        ((ushort_t*)out)[addr] = f2bf(acc);
}

extern "C" void kernel_launch(void* const* d_in, const int* in_sizes, int n_in,
                              void* d_out, int out_size, void* d_ws, size_t ws_size,
                              hipStream_t stream)
{
    (void)in_sizes; (void)n_in; (void)out_size; (void)ws_size;
    const void* x   = d_in[0];
    const void* wq  = d_in[1];
    const void* bq  = d_in[2];
    const void* wk  = d_in[3];
    const void* bk  = d_in[4];
    const void* wv  = d_in[5];
    const void* bv  = d_in[6];
    const void* wo  = d_in[7];
    const void* bo  = d_in[8];
    const void* pos = d_in[9];

    int*   flag  = (int*)d_ws;
    float* qslab = (float*)((char*)d_ws + 256);
    float* kslab = qslab + SLABF;
    float* vslab = kslab + SLABF;          // total ws use: 256 B + 3.54 MB

    detect_dtype<<<1, 256, 0, stream>>>((const ushort_t*)wq, flag);

    for (int b = 0; b < 2; ++b) {
        for (int t = 0; t < 16; ++t) {
            proj_qkv_naive<<<dim3(1152, 3), 256, 0, stream>>>(
                x, pos, wq, bq, wk, bk, wv, bv,
                qslab, kslab, vslab, flag, b, t);
            attn_naive<<<dim3(3, 8), 192, 0, stream>>>(qslab, kslab, vslab);
            proj_out_naive<<<dim3(1152), 256, 0, stream>>>(
                qslab, wo, bo, d_out, flag, b, t);
        }
    }
}